// Round 9
// baseline (2223.461 us; speedup 1.0000x reference)
//
#include <hip/hip_runtime.h>

// RNNModule: LSTM-like scan with shared gate pre-activation.
// B=128, L=256, D=512, H=1024, O=2.
//
//  k2 exchange protocol (R9):
//   producer: h plain-store (XCD-local L2, write-through L1) + sc1 store (L3
//             truth) -> vmcnt(0) -> WG barrier -> tid0 dual-stores WG flag.
//   consumer: wave0 polls 16 WG-flags with sc0 (L2 fast path; blk&7 groups
//             match round-robin XCD placement), every 8th round sc0+sc1 (L3)
//             -- guarantees progress under ANY WG->XCD mapping. Flag visible
//             anywhere => sc1 data ack'd in L3 => sc0 data fills can never be
//             stale => bulk 32 KB staging uses plain-fast sc0 loads into LDS.
//  R4's failure ("sc1 store skips local L2 -> sc0 polls spin on stale fills")
//  is exactly what the dual store fixes.

#define B_ 128
#define L_ 256
#define D_ 512
#define H_ 1024

typedef __attribute__((ext_vector_type(8))) short short8;
typedef __attribute__((ext_vector_type(4))) float f32x4;
typedef __attribute__((ext_vector_type(2))) float f32x2;
typedef __attribute__((ext_vector_type(4))) unsigned short u16x4;
typedef __attribute__((ext_vector_type(4))) int i32x4;

__device__ __forceinline__ unsigned short f2bf(float f) {
    unsigned int u = __float_as_uint(f);
    return (unsigned short)((u + 0x8000u) >> 16);  // round-half-up to bf16
}
__device__ __forceinline__ float bf2f(unsigned short s) {
    return __uint_as_float(((unsigned int)s) << 16);
}

// agent-scope 8B atomic store: write-through to the coherence point (L3)
__device__ __forceinline__ void st8_ag(unsigned short* p, unsigned long long v) {
    __hip_atomic_store((unsigned long long*)p, v,
                       __ATOMIC_RELAXED, __HIP_MEMORY_SCOPE_AGENT);
}
// plain 8B store: lands in the XCD-local L2 (L1 is write-through)
__device__ __forceinline__ void st8_wg(unsigned short* p, unsigned long long v) {
    *(volatile unsigned long long*)p = v;
}

// flag loads (wait folded in so the compiler can't misplace it)
__device__ __forceinline__ int ld_flag_l2(const int* p) {
    int r;
    asm volatile("global_load_dword %0, %1, off sc0\n\ts_waitcnt vmcnt(0)"
                 : "=v"(r) : "v"(p) : "memory");
    return r;
}
__device__ __forceinline__ int ld_flag_l3(const int* p) {
    int r;
    asm volatile("global_load_dword %0, %1, off sc0 sc1\n\ts_waitcnt vmcnt(0)"
                 : "=v"(r) : "v"(p) : "memory");
    return r;
}

// 16B staging load: sc0 (bypass L1, hit local L2 / fill-from-L3 both fresh
// once the flag has been observed -- see protocol proof above)
template<int OFF>
__device__ __forceinline__ i32x4 ld16_l2(const unsigned short* p) {
    i32x4 r;
    asm volatile("global_load_dwordx4 %0, %1, off offset:%2 sc0"
                 : "=v"(r) : "v"(p), "i"(OFF) : "memory");
    return r;
}
__device__ __forceinline__ void wait_vm4(i32x4& a, i32x4& b, i32x4& c, i32x4& d) {
    asm volatile("s_waitcnt vmcnt(4)" : "+v"(a), "+v"(b), "+v"(c), "+v"(d) :: "memory");
}
__device__ __forceinline__ void wait_vm0(i32x4& a, i32x4& b, i32x4& c, i32x4& d) {
    asm volatile("s_waitcnt vmcnt(0)" : "+v"(a), "+v"(b), "+v"(c), "+v"(d) :: "memory");
}
__device__ __forceinline__ void release_vm0() {
    asm volatile("s_waitcnt vmcnt(0)" ::: "memory");
}

// ---------------------------------------------------------------- k0: prep
// blk<256: Wh 64x64 tile transpose; blk<384: Wx tiles; blk 384: bxh+flags.
__global__ __launch_bounds__(256) void k0_prep(
    const float* __restrict__ Wh, const float* __restrict__ Wx,
    const float* __restrict__ bh, const float* __restrict__ bx,
    unsigned short* __restrict__ Whb_t, unsigned short* __restrict__ Wxb_t,
    float* __restrict__ bxh, int* __restrict__ bar)
{
    __shared__ float tile[64][65];
    const int blk = blockIdx.x;
    const int t   = threadIdx.x;
    const int c   = t & 63, r0 = t >> 6;

    if (blk < 256) {            // Wh (1024x1024) -> Whb_t[n][k]
        const int tk = (blk >> 4) * 64, tn = (blk & 15) * 64;
#pragma unroll
        for (int i = 0; i < 16; ++i) {
            int r = i * 4 + r0;
            tile[r][c] = Wh[(size_t)(tk + r) * H_ + tn + c];
        }
        __syncthreads();
#pragma unroll
        for (int i = 0; i < 16; ++i) {
            int r = i * 4 + r0;
            Whb_t[(size_t)(tn + r) * H_ + tk + c] = f2bf(tile[c][r]);
        }
    } else if (blk < 384) {     // Wx (512x1024) -> Wxb_t[n][k]
        const int bi = blk - 256;
        const int tk = (bi >> 4) * 64, tn = (bi & 15) * 64;
#pragma unroll
        for (int i = 0; i < 16; ++i) {
            int r = i * 4 + r0;
            tile[r][c] = Wx[(size_t)(tk + r) * H_ + tn + c];
        }
        __syncthreads();
#pragma unroll
        for (int i = 0; i < 16; ++i) {
            int r = i * 4 + r0;
            Wxb_t[(size_t)(tn + r) * D_ + tk + c] = f2bf(tile[c][r]);
        }
    } else {
        for (int i = t; i < H_; i += 256) bxh[i] = bx[i] + bh[i];
        for (int i = t; i < 8 * 1024; i += 256) bar[i] = 0;
    }
}

// ------------------------------------------------------------ k1: x @ Wx
// M-tile 128 (one l, all 128 batch rows) x N-tile 256: each B fragment now
// feeds TWO m-subtiles -> B-fragment L2 traffic halves vs R8 (537->268 MB).
__global__ __launch_bounds__(256, 1) void k1_xproj(
    const float* __restrict__ x, const unsigned short* __restrict__ Wxb_t,
    const float* __restrict__ bxh, unsigned short* __restrict__ xp)
{
    const int nt   = blockIdx.x & 3;
    const int l    = blockIdx.x >> 2;        // 256
    const int w    = threadIdx.x >> 6;
    const int lane = threadIdx.x & 63;
    const int m    = lane & 15, q = lane >> 4;
    const int n0   = nt * 256;
    const int b0   = w * 32;                 // wave's 32 batch rows (2 subtiles)

    const float* ap0 = x + ((size_t)(b0 + m) * L_ + l) * D_ + q * 8;
    const float* ap1 = ap0 + (size_t)16 * L_ * D_;

    f32x4 acc0[16], acc1[16];
#pragma unroll
    for (int t = 0; t < 16; ++t) {
        acc0[t] = (f32x4){0.f, 0.f, 0.f, 0.f};
        acc1[t] = (f32x4){0.f, 0.f, 0.f, 0.f};
    }

#pragma unroll 4
    for (int kk = 0; kk < 16; ++kk) {
        f32x4 a0lo = *(const f32x4*)(ap0 + kk * 32);
        f32x4 a0hi = *(const f32x4*)(ap0 + kk * 32 + 4);
        f32x4 a1lo = *(const f32x4*)(ap1 + kk * 32);
        f32x4 a1hi = *(const f32x4*)(ap1 + kk * 32 + 4);
        short8 a80, a81;
#pragma unroll
        for (int j = 0; j < 4; ++j) {
            a80[j]     = (short)f2bf(a0lo[j]); a80[j + 4] = (short)f2bf(a0hi[j]);
            a81[j]     = (short)f2bf(a1lo[j]); a81[j + 4] = (short)f2bf(a1hi[j]);
        }
#pragma unroll
        for (int t = 0; t < 16; ++t) {
            short8 b8 = *(const short8*)(Wxb_t +
                        (size_t)(n0 + t * 16 + m) * D_ + kk * 32 + q * 8);
            acc0[t] = __builtin_amdgcn_mfma_f32_16x16x32_bf16(b8, a80, acc0[t], 0, 0, 0);
            acc1[t] = __builtin_amdgcn_mfma_f32_16x16x32_bf16(b8, a81, acc1[t], 0, 0, 0);
        }
    }

#pragma unroll
    for (int t = 0; t < 16; ++t) {
        const int c0 = n0 + t * 16 + q * 4;       // 4 consecutive out-cols
        f32x4 bias = *(const f32x4*)(bxh + c0);
        u16x4 o0, o1;
#pragma unroll
        for (int r = 0; r < 4; ++r) {
            o0[r] = f2bf(acc0[t][r] + bias[r]);
            o1[r] = f2bf(acc1[t][r] + bias[r]);
        }
        *(u16x4*)(xp + ((size_t)l * B_ + b0 + m) * H_ + c0)      = o0;
        *(u16x4*)(xp + ((size_t)l * B_ + b0 + 16 + m) * H_ + c0) = o1;
    }
}

// ------------------------------------------------------------- k2: scan
// Grid: 128 WGs x 256 thr. group g=blk&7 (batch rows g*16..+15; matches the
// round-robin XCD under measured dispatch -- speed heuristic only, escalation
// keeps it correct), wg=blk>>3 in [0,16) (cols wg*64..+63; wave owns 16).
__global__ __launch_bounds__(256, 1) void k2_scan(
    const unsigned short* __restrict__ Whb_t,
    const unsigned short* __restrict__ xp,
    unsigned short* __restrict__ hs,
    int* __restrict__ bar)
{
    // rows padded to 1034 shorts (517 dwords): bank stride 5 per row ->
    // ~2-way (free) patterns on both staging writes and b128 fragment reads
    // (1032's stride-4 gave 8-way: the measured 1.67e7 conflict cycles).
    __shared__ unsigned short buf[2][16][1034];

    const int g    = blockIdx.x & 7;
    const int wg   = blockIdx.x >> 3;        // 0..15
    const int tid  = threadIdx.x;
    const int w    = tid >> 6;               // 0..3
    const int lane = tid & 63;
    const int mb   = lane & 15, q = lane >> 4;
    const int b0   = g * 16;
    const int colw = wg * 64 + w * 16;       // wave's 16-col tile

    // persistent A fragments: Wh^T[colw+mb][k], opaque loads (no remat)
    short8 afrag[32];
    {
        const unsigned short* wp = Whb_t + (size_t)(colw + mb) * H_ + q * 8;
#pragma unroll
        for (int kk = 0; kk < 32; ++kk)
            asm volatile("global_load_dwordx4 %0, %1, off offset:%2"
                         : "=v"(afrag[kk]) : "v"(wp), "i"(kk * 64));
        asm volatile("s_waitcnt vmcnt(0)" ::: "memory");
#pragma unroll
        for (int kk = 0; kk < 32; ++kk)
            asm volatile("" : "+v"(afrag[kk]));
    }

    int* flags  = bar + g * 1024;            // 16 WG-flags, stride 32 ints (128B)
    int* myflag = flags + wg * 32;

    // staging mapping: thread -> row srow, 16B-chunks sci + 16i (i<8)
    const int srow = tid >> 4;   // 0..15
    const int sci  = tid & 15;   // 0..15

    float c[4] = {0.f, 0.f, 0.f, 0.f};

    for (int l = 0; l < L_; ++l) {
        // xp addend (independent of recurrence): issue early
        u16x4 xv = *(const u16x4*)(xp + ((size_t)l * B_ + b0 + mb) * H_ + colw + q * 4);

        unsigned short* lbuf = &buf[l & 1][0][0];
        if (l > 0) {
            // wave0 polls the 16 WG-flags: sc0 fast path (local L2), every
            // 8th round sc0+sc1 (L3 truth) -> progress under any placement.
            if (w == 0) {
                const int* fp = flags + lane * 32;   // lanes 0..15 active
                int round = 0;
                for (;;) {
                    int f = l;
                    if (lane < 16)
                        f = ((++round & 7) == 0) ? ld_flag_l3(fp) : ld_flag_l2(fp);
                    if (__all(f >= l)) break;
                }
            }
            __syncthreads();   // A: flags observed -> data fetchable via sc0
            // stage h[l-1] slice (16 x 1024, 32 KB) -> LDS, split drain
            const unsigned short* gp =
                hs + ((size_t)(l - 1) * B_ + b0 + srow) * H_ + sci * 8;
            i32x4 v0, v1, v2, v3, v4, v5, v6, v7;
            v0 = ld16_l2<0>(gp);    v1 = ld16_l2<256>(gp);
            v2 = ld16_l2<512>(gp);  v3 = ld16_l2<768>(gp);
            v4 = ld16_l2<1024>(gp); v5 = ld16_l2<1280>(gp);
            v6 = ld16_l2<1536>(gp); v7 = ld16_l2<1792>(gp);
            unsigned short* lp = lbuf + srow * 1034 + sci * 8;
            wait_vm4(v0, v1, v2, v3);
            *(i32x4*)(lp)        = v0;  *(i32x4*)(lp + 128)  = v1;
            *(i32x4*)(lp + 256)  = v2;  *(i32x4*)(lp + 384)  = v3;
            wait_vm0(v4, v5, v6, v7);
            *(i32x4*)(lp + 512)  = v4;  *(i32x4*)(lp + 640)  = v5;
            *(i32x4*)(lp + 768)  = v6;  *(i32x4*)(lp + 896)  = v7;
        }
        __syncthreads();       // B: staging visible; dbuf protects step l+1

        f32x4 acc0 = {0.f,0.f,0.f,0.f}, acc1 = {0.f,0.f,0.f,0.f};
        f32x4 acc2 = {0.f,0.f,0.f,0.f}, acc3 = {0.f,0.f,0.f,0.f};
        if (l > 0) {
            const unsigned short* rp = lbuf + mb * 1034 + q * 8;
#pragma unroll
            for (int kb = 0; kb < 32; kb += 4) {
                short8 bb0 = *(const short8*)(rp + (kb + 0) * 32);
                short8 bb1 = *(const short8*)(rp + (kb + 1) * 32);
                short8 bb2 = *(const short8*)(rp + (kb + 2) * 32);
                short8 bb3 = *(const short8*)(rp + (kb + 3) * 32);
                acc0 = __builtin_amdgcn_mfma_f32_16x16x32_bf16(afrag[kb + 0], bb0, acc0, 0, 0, 0);
                acc1 = __builtin_amdgcn_mfma_f32_16x16x32_bf16(afrag[kb + 1], bb1, acc1, 0, 0, 0);
                acc2 = __builtin_amdgcn_mfma_f32_16x16x32_bf16(afrag[kb + 2], bb2, acc2, 0, 0, 0);
                acc3 = __builtin_amdgcn_mfma_f32_16x16x32_bf16(afrag[kb + 3], bb3, acc3, 0, 0, 0);
            }
        }
        // gate math: lane (mb,q) -> batch b0+mb, cols colw+q*4+r
        u16x4 o;
#pragma unroll
        for (int r = 0; r < 4; ++r) {
            float z  = acc0[r] + acc1[r] + acc2[r] + acc3[r] + bf2f(xv[r]);
            float e  = __expf(-z);
            float sg = 1.f / (1.f + e);           // sigmoid(z)
            float gg = 2.f / (1.f + e * e) - 1.f; // tanh(z) via same exp
            c[r] = sg * (c[r] + gg);
            float ec = __expf(-2.f * c[r]);
            float th = 2.f / (1.f + ec) - 1.f;    // tanh(c)
            o[r] = f2bf(sg * th);
        }
        union { u16x4 v; unsigned long long u; } hu;
        hu.v = o;
        unsigned short* hp = hs + ((size_t)l * B_ + b0 + mb) * H_ + colw + q * 4;
        st8_wg(hp, hu.u);      // local-L2 fast copy (write-through L1)
        st8_ag(hp, hu.u);      // L3 truth
        release_vm0();         // both acks before the flag can exist anywhere
        __syncthreads();       // C: ALL waves' stores ack'd
        if (tid == 0) {
            *(volatile int*)myflag = l + 1;                       // L2 fast flag
            __hip_atomic_store(myflag, l + 1,
                               __ATOMIC_RELAXED, __HIP_MEMORY_SCOPE_AGENT); // L3
        }
    }
}

// ------------------------------------------------------------- k3: output
__global__ __launch_bounds__(256) void k3_out(
    const unsigned short* __restrict__ hs,
    const float* __restrict__ Wo, const float* __restrict__ bo,
    const int* __restrict__ slen, float* __restrict__ out)
{
    const int w    = threadIdx.x >> 6;
    const int lane = threadIdx.x & 63;
    const int r    = blockIdx.x * 4 + w;   // r = b*L + l
    const int b    = r >> 8;
    const int l    = r & 255;

    const unsigned short* hp = hs + ((size_t)l * B_ + b) * H_ + lane * 16;
    const float* wp = Wo + (size_t)lane * 32;
    float u0 = 0.f, u1 = 0.f;
#pragma unroll
    for (int j0 = 0; j0 < 16; j0 += 8) {
        short8 hv = *(const short8*)(hp + j0);
#pragma unroll
        for (int j = 0; j < 8; ++j) {
            float h = bf2f((unsigned short)hv[j]);
            f32x2 wv = *(const f32x2*)(wp + (j0 + j) * 2);
            u0 += h * wv[0];
            u1 += h * wv[1];
        }
    }
#pragma unroll
    for (int off = 32; off; off >>= 1) {
        u0 += __shfl_down(u0, off);
        u1 += __shfl_down(u1, off);
    }
    if (lane == 0) {
        float o0, o1;
        if (l <= slen[b]) {
            o0 = 1.f / (1.f + __expf(-(u0 + bo[0])));
            o1 = 1.f / (1.f + __expf(-(u1 + bo[1])));
        } else {
            o0 = 0.f; o1 = 1.f;
        }
        out[(size_t)r * 2]     = o0;
        out[(size_t)r * 2 + 1] = o1;
    }
}

// ----------------------------------------------------------------- launch
extern "C" void kernel_launch(void* const* d_in, const int* in_sizes, int n_in,
                              void* d_out, int out_size, void* d_ws, size_t ws_size,
                              hipStream_t stream)
{
    const float* x    = (const float*)d_in[0];
    const int*   slen = (const int*)d_in[1];
    const float* Wh   = (const float*)d_in[2];
    const float* bh   = (const float*)d_in[3];
    const float* Wx   = (const float*)d_in[4];
    const float* bx   = (const float*)d_in[5];
    const float* Wo   = (const float*)d_in[6];
    const float* bo   = (const float*)d_in[7];
    float* out = (float*)d_out;

    char* ws = (char*)d_ws;
    unsigned short* Whb_t = (unsigned short*)(ws);                     // 2 MiB
    unsigned short* Wxb_t = (unsigned short*)(ws + (2u << 20));        // 1 MiB
    float*          bxh   = (float*)(ws + (3u << 20));                 // 4 KiB
    int*            bar   = (int*)(ws + (3u << 20) + 65536);           // 32 KiB
    unsigned short* xp    = (unsigned short*)(ws + (4u << 20));        // 64 MiB
    unsigned short* hs    = (unsigned short*)(ws + (68u << 20));       // 64 MiB

    k0_prep<<<385, 256, 0, stream>>>(Wh, Wx, bh, bx, Whb_t, Wxb_t, bxh, bar);
    k1_xproj<<<1024, 256, 0, stream>>>(x, Wxb_t, bxh, xp);
    k2_scan<<<128, 256, 0, stream>>>(Whb_t, xp, hs, bar);
    k3_out<<<8192, 256, 0, stream>>>(hs, Wo, bo, slen, out);
}